// Round 2
// baseline (1263.017 us; speedup 1.0000x reference)
//
#include <hip/hip_runtime.h>
#include <hip/hip_bf16.h>
#include <math.h>

// Problem constants (fixed by the reference)
#define N_NODES 100000
#define N_EDGES 1600000
#define NFEAT 128
#define NHID  64
#define NCLASS 40
#define NL 6
#define NBUCK 8
#define BUCK_SZ (N_NODES / NBUCK)  // 12500

__device__ __forceinline__ float rdlane(float v, int l) {
  return __int_as_float(__builtin_amdgcn_readlane(__float_as_int(v), l));
}
__device__ __forceinline__ float bf2f(__hip_bfloat16 b) { return __bfloat162float(b); }

// ---------------------------------------------------------------------------
// CSR build: histogram -> exclusive scan -> bucketed scatter (packed {col,val})
// ---------------------------------------------------------------------------
__global__ void zero_cnt_k(int* __restrict__ cnt) {
  int i = blockIdx.x * 256 + threadIdx.x;
  if (i < N_NODES) cnt[i] = 0;
}

__global__ void hist_k(const int* __restrict__ row, int* __restrict__ cnt) {
  int e = blockIdx.x * 256 + threadIdx.x;
  if (e < N_EDGES) atomicAdd(&cnt[row[e]], 1);
}

__global__ __launch_bounds__(1024) void scan1_k(const int* __restrict__ cnt,
                                                int* __restrict__ rp,
                                                int* __restrict__ bsum) {
  __shared__ int sd[1024];
  int t = threadIdx.x;
  int idx = blockIdx.x * 1024 + t;
  int v = (idx < N_NODES) ? cnt[idx] : 0;
  sd[t] = v;
  __syncthreads();
  for (int off = 1; off < 1024; off <<= 1) {
    int add = (t >= off) ? sd[t - off] : 0;
    __syncthreads();
    sd[t] += add;
    __syncthreads();
  }
  if (idx < N_NODES) rp[idx] = sd[t] - v;   // exclusive
  if (t == 0) bsum[blockIdx.x] = sd[1023];  // block total
}

__global__ void scan2_k(int* __restrict__ bsum, int nb) {
  if (threadIdx.x == 0 && blockIdx.x == 0) {
    int run = 0;
    for (int i = 0; i < nb; ++i) { int x = bsum[i]; bsum[i] = run; run += x; }
  }
}

__global__ void scan3_k(int* __restrict__ rp, int* __restrict__ cur,
                        const int* __restrict__ bsum) {
  int i = blockIdx.x * 256 + threadIdx.x;
  if (i < N_NODES) {
    int v = rp[i] + bsum[i >> 10];
    rp[i] = v;
    cur[i] = v;  // scatter cursor starts at row base
  }
  if (i == 0) rp[N_NODES] = N_EDGES;
}

// Bucketed scatter: bucket class = blockIdx%8 (heuristically maps to one XCD
// under round-robin dispatch). Each class writes only a contiguous ~1.6 MB
// destination region -> writes stay L2-resident, evict as full lines.
// Correct regardless of actual block->XCD mapping (locality is best-effort).
__global__ __launch_bounds__(256) void scatter_k(const int* __restrict__ row,
                                                 const int* __restrict__ col,
                                                 const float* __restrict__ val,
                                                 int* __restrict__ cur,
                                                 int2* __restrict__ ep) {
  const int bclass = blockIdx.x & (NBUCK - 1);
  const int chunk  = blockIdx.x >> 3;
  const int nchunk = gridDim.x >> 3;
  const int per = (N_EDGES + nchunk - 1) / nchunk;
  const int e0 = chunk * per;
  const int e1 = min(e0 + per, N_EDGES);
  for (int e = e0 + threadIdx.x; e < e1; e += 256) {
    int r = row[e];
    if ((r / BUCK_SZ) == bclass) {
      int p = atomicAdd(&cur[r], 1);
      ep[p] = make_int2(col[e], __float_as_int(val[e]));
    }
  }
}

// ---------------------------------------------------------------------------
// GEMM (layer 1 only): x[N,128] @ W1[128,64] -> Sa[N,64] (bf16 out).
// Wave-per-8-rows; W column in VGPRs; H broadcast via readlane.
// ---------------------------------------------------------------------------
__global__ __launch_bounds__(256) void gemm128_k(const float* __restrict__ H,
                                                 const float* __restrict__ W,
                                                 __hip_bfloat16* __restrict__ S) {
  const int lane = threadIdx.x & 63;
  float wreg[128];
#pragma unroll
  for (int k = 0; k < 128; ++k) wreg[k] = W[k * 64 + lane];

  const int nrg = N_NODES / 8;  // 12500
  for (int rg = blockIdx.x * 4 + (threadIdx.x >> 6); rg < nrg; rg += gridDim.x * 4) {
    const int r0 = rg * 8;
    float hreg[8][2];
#pragma unroll
    for (int i = 0; i < 8; ++i)
#pragma unroll
      for (int p = 0; p < 2; ++p)
        hreg[i][p] = H[(size_t)(r0 + i) * 128 + p * 64 + lane];

    float acc[8];
#pragma unroll
    for (int i = 0; i < 8; ++i) acc[i] = 0.0f;

#pragma unroll
    for (int p = 0; p < 2; ++p)
#pragma unroll
      for (int k = 0; k < 64; ++k) {
        const float w = wreg[p * 64 + k];
#pragma unroll
        for (int i = 0; i < 8; ++i)
          acc[i] = fmaf(rdlane(hreg[i][p], k), w, acc[i]);
      }

#pragma unroll
    for (int i = 0; i < 8; ++i)
      S[(size_t)(r0 + i) * 64 + lane] = __float2bfloat16(acc[i]);
  }
}

// ---------------------------------------------------------------------------
// Fused SpMM + epilogue-GEMM. Wave per node, lane = feature.
//   agg = sum_e val_e * Sin[col_e][:]        (bf16 gather, fp32 acc)
//   h   = relu(agg + bias) [+ res]           (res read/write same element: safe in-place)
//   if STOREH: Hout[node] = h                (fp32, residual consumer 2 layers later)
//   Sout[node][j] = sum_k h[k] * Wn[k][j]    (readlane broadcast, bf16 out, NEXTC wide)
// ---------------------------------------------------------------------------
template <bool RES, bool STOREH, int NEXTC>
__global__ __launch_bounds__(256) void spmm_fused_k(
    const __hip_bfloat16* __restrict__ Sin, const int2* __restrict__ ep,
    const int* __restrict__ rp, const float* __restrict__ bias,
    const float* __restrict__ res, float* __restrict__ Hout,
    const float* __restrict__ Wn, __hip_bfloat16* __restrict__ Sout) {
  const int lane = threadIdx.x & 63;
  const int node = blockIdx.x * 4 + (threadIdx.x >> 6);

  // next-layer weight column for this lane
  float wreg[64];
#pragma unroll
  for (int k = 0; k < 64; ++k)
    wreg[k] = (NEXTC == 64 || lane < NEXTC) ? Wn[k * NEXTC + lane] : 0.0f;

  const int start = rp[node], end = rp[node + 1];
  float a0 = 0.0f, a1 = 0.0f;
  int e = start;
  for (; e + 4 <= end; e += 4) {
    int2 e0 = ep[e + 0], e1 = ep[e + 1], e2 = ep[e + 2], e3 = ep[e + 3];
    a0 = fmaf(__int_as_float(e0.y), bf2f(Sin[(size_t)e0.x * 64 + lane]), a0);
    a1 = fmaf(__int_as_float(e1.y), bf2f(Sin[(size_t)e1.x * 64 + lane]), a1);
    a0 = fmaf(__int_as_float(e2.y), bf2f(Sin[(size_t)e2.x * 64 + lane]), a0);
    a1 = fmaf(__int_as_float(e3.y), bf2f(Sin[(size_t)e3.x * 64 + lane]), a1);
  }
  for (; e < end; ++e) {
    int2 ee = ep[e];
    a0 = fmaf(__int_as_float(ee.y), bf2f(Sin[(size_t)ee.x * 64 + lane]), a0);
  }

  float h = fmaxf(a0 + a1 + bias[lane], 0.0f);
  if (RES) h += res[(size_t)node * 64 + lane];
  if (STOREH) Hout[(size_t)node * 64 + lane] = h;

  float s = 0.0f;
#pragma unroll
  for (int k = 0; k < 64; ++k) s = fmaf(rdlane(h, k), wreg[k], s);

  if (NEXTC == 64 || lane < NEXTC)
    Sout[(size_t)node * NEXTC + lane] = __float2bfloat16(s);
}

// Final: SpMM (40-wide bf16 gather) + bias + log_softmax, writes d_out.
__global__ __launch_bounds__(256) void spmm_final_k(const __hip_bfloat16* __restrict__ S40,
                                                    const int2* __restrict__ ep,
                                                    const int* __restrict__ rp,
                                                    const float* __restrict__ b2,
                                                    float* __restrict__ out) {
  const int lane = threadIdx.x & 63;
  const int node = blockIdx.x * 4 + (threadIdx.x >> 6);
  const int start = rp[node], end = rp[node + 1];

  float a0 = 0.0f, a1 = 0.0f;
  int e = start;
  for (; e + 2 <= end; e += 2) {
    int2 e0 = ep[e], e1 = ep[e + 1];
    // lanes >= 40 read a few elements past the 40-wide logical array but stay
    // inside the (64-wide-sized) allocation; values masked from reductions.
    a0 = fmaf(__int_as_float(e0.y), bf2f(S40[(size_t)e0.x * 40 + lane]), a0);
    a1 = fmaf(__int_as_float(e1.y), bf2f(S40[(size_t)e1.x * 40 + lane]), a1);
  }
  for (; e < end; ++e) {
    int2 ee = ep[e];
    a0 = fmaf(__int_as_float(ee.y), bf2f(S40[(size_t)ee.x * 40 + lane]), a0);
  }

  float logit = a0 + a1 + ((lane < NCLASS) ? b2[lane] : 0.0f);
  float mx = (lane < NCLASS) ? logit : -INFINITY;
#pragma unroll
  for (int off = 32; off; off >>= 1) mx = fmaxf(mx, __shfl_xor(mx, off));
  float ex = (lane < NCLASS) ? expf(logit - mx) : 0.0f;
  float sum = ex;
#pragma unroll
  for (int off = 32; off; off >>= 1) sum += __shfl_xor(sum, off);
  if (lane < NCLASS) out[(size_t)node * NCLASS + lane] = logit - mx - logf(sum);
}

// ---------------------------------------------------------------------------
extern "C" void kernel_launch(void* const* d_in, const int* in_sizes, int n_in,
                              void* d_out, int out_size, void* d_ws, size_t ws_size,
                              hipStream_t stream) {
  const float* x    = (const float*)d_in[0];
  const int*   erow = (const int*)d_in[1];
  const int*   ecol = (const int*)d_in[2];
  const float* eval = (const float*)d_in[3];
  const float* W1   = (const float*)d_in[4];
  const float* b1   = (const float*)d_in[5];
  const float* Wm   = (const float*)d_in[6];
  const float* bm   = (const float*)d_in[7];
  const float* W2   = (const float*)d_in[8];
  const float* b2   = (const float*)d_in[9];
  float* out = (float*)d_out;

  // Workspace layout (~90.4 MB total — same footprint as the known-good R1)
  char* ws = (char*)d_ws;
  size_t off = 0;
  auto alloc = [&](size_t bytes) {
    void* p = ws + off;
    off = (off + bytes + 255) & ~(size_t)255;
    return p;
  };
  int*   rp   = (int*)alloc((N_NODES + 1) * sizeof(int));
  int*   cur  = (int*)alloc(N_NODES * sizeof(int));
  int*   bsum = (int*)alloc(128 * sizeof(int));
  int2*  ep   = (int2*)alloc((size_t)N_EDGES * sizeof(int2));
  __hip_bfloat16* Sa = (__hip_bfloat16*)alloc((size_t)N_NODES * 64 * sizeof(__hip_bfloat16));
  __hip_bfloat16* Sb = (__hip_bfloat16*)alloc((size_t)N_NODES * 64 * sizeof(__hip_bfloat16));
  float* H0 = (float*)alloc((size_t)N_NODES * 64 * sizeof(float));
  float* H1 = (float*)alloc((size_t)N_NODES * 64 * sizeof(float));

  const int ZB = (N_NODES + 255) / 256;   // 391
  const int EB = N_EDGES / 256;           // 6250 (exact)
  const int SB = (N_NODES + 1023) / 1024; // 98
  const int SCAT_B = NBUCK * 800;         // 8 classes x 800 chunks of 2000 edges
  const int SPMM_GRID = N_NODES / 4;      // 25000 (exact)

  // CSR build (same adjacency reused by all 8 layers)
  zero_cnt_k<<<ZB, 256, 0, stream>>>(cur);
  hist_k<<<EB, 256, 0, stream>>>(erow, cur);
  scan1_k<<<SB, 1024, 0, stream>>>(cur, rp, bsum);
  scan2_k<<<1, 64, 0, stream>>>(bsum, SB);
  scan3_k<<<ZB, 256, 0, stream>>>(rp, cur, bsum);
  scatter_k<<<SCAT_B, 256, 0, stream>>>(erow, ecol, eval, cur, ep);

  // S1 = x @ W1  (bf16)
  gemm128_k<<<1024, 256, 0, stream>>>(x, W1, Sa);

  // L1: h1 = relu(A Sa + b1) -> H0;  Sb = h1 @ Wm[0]
  spmm_fused_k<false, true, 64><<<SPMM_GRID, 256, 0, stream>>>(
      Sa, ep, rp, b1, nullptr, H0, Wm + 0 * 4096, Sb);
  // L2: h2 = relu(A Sb + bm0) -> H1;  Sa = h2 @ Wm[1]
  spmm_fused_k<false, true, 64><<<SPMM_GRID, 256, 0, stream>>>(
      Sb, ep, rp, bm + 0 * 64, nullptr, H1, Wm + 1 * 4096, Sa);
  // L3: h3 = relu(A Sa + bm1) + h1 -> H0 (in-place);  Sb = h3 @ Wm[2]
  spmm_fused_k<true, true, 64><<<SPMM_GRID, 256, 0, stream>>>(
      Sa, ep, rp, bm + 1 * 64, H0, H0, Wm + 2 * 4096, Sb);
  // L4: h4 = relu(A Sb + bm2) + h2 -> H1;  Sa = h4 @ Wm[3]
  spmm_fused_k<true, true, 64><<<SPMM_GRID, 256, 0, stream>>>(
      Sb, ep, rp, bm + 2 * 64, H1, H1, Wm + 3 * 4096, Sa);
  // L5: h5 = relu(A Sa + bm3) + h3 -> H0;  Sb = h5 @ Wm[4]
  spmm_fused_k<true, true, 64><<<SPMM_GRID, 256, 0, stream>>>(
      Sa, ep, rp, bm + 3 * 64, H0, H0, Wm + 4 * 4096, Sb);
  // L6: h6 = relu(A Sb + bm4) + h4 (not stored);  Sa = h6 @ Wm[5]
  spmm_fused_k<true, false, 64><<<SPMM_GRID, 256, 0, stream>>>(
      Sb, ep, rp, bm + 4 * 64, H1, nullptr, Wm + 5 * 4096, Sa);
  // L7: h7 = relu(A Sa + bm5) + h5 (not stored);  Sb(40) = h7 @ W2
  spmm_fused_k<true, false, 40><<<SPMM_GRID, 256, 0, stream>>>(
      Sa, ep, rp, bm + 5 * 64, H0, nullptr, W2, Sb);

  // out = log_softmax(A Sb40 + b2)
  spmm_final_k<<<SPMM_GRID, 256, 0, stream>>>(Sb, ep, rp, b2, out);
}

// Round 3
// 887.127 us; speedup vs baseline: 1.4237x; 1.4237x over previous
//
#include <hip/hip_runtime.h>
#include <hip/hip_bf16.h>
#include <math.h>

// Problem constants (fixed by the reference)
#define N_NODES 100000
#define N_EDGES 1600000
#define NFEAT 128
#define NHID  64
#define NCLASS 40
#define NL 6
#define NBUCK 8
#define BUCK_SZ (N_NODES / NBUCK)  // 12500

__device__ __forceinline__ float rdlane(float v, int l) {
  return __int_as_float(__builtin_amdgcn_readlane(__float_as_int(v), l));
}
__device__ __forceinline__ float bfbits(unsigned short u) {
  return __uint_as_float((unsigned int)u << 16);
}

// ---------------------------------------------------------------------------
// CSR build: histogram -> exclusive scan -> bucketed scatter (packed {col,val})
// ---------------------------------------------------------------------------
__global__ void zero_cnt_k(int* __restrict__ cnt) {
  int i = blockIdx.x * 256 + threadIdx.x;
  if (i < N_NODES) cnt[i] = 0;
}

__global__ void hist_k(const int* __restrict__ row, int* __restrict__ cnt) {
  int e = blockIdx.x * 256 + threadIdx.x;
  if (e < N_EDGES) atomicAdd(&cnt[row[e]], 1);
}

__global__ __launch_bounds__(1024) void scan1_k(const int* __restrict__ cnt,
                                                int* __restrict__ rp,
                                                int* __restrict__ bsum) {
  __shared__ int sd[1024];
  int t = threadIdx.x;
  int idx = blockIdx.x * 1024 + t;
  int v = (idx < N_NODES) ? cnt[idx] : 0;
  sd[t] = v;
  __syncthreads();
  for (int off = 1; off < 1024; off <<= 1) {
    int add = (t >= off) ? sd[t - off] : 0;
    __syncthreads();
    sd[t] += add;
    __syncthreads();
  }
  if (idx < N_NODES) rp[idx] = sd[t] - v;   // exclusive
  if (t == 0) bsum[blockIdx.x] = sd[1023];  // block total
}

__global__ void scan2_k(int* __restrict__ bsum, int nb) {
  if (threadIdx.x == 0 && blockIdx.x == 0) {
    int run = 0;
    for (int i = 0; i < nb; ++i) { int x = bsum[i]; bsum[i] = run; run += x; }
  }
}

__global__ void scan3_k(int* __restrict__ rp, int* __restrict__ cur,
                        const int* __restrict__ bsum, int2* __restrict__ ep) {
  int i = blockIdx.x * 256 + threadIdx.x;
  if (i < N_NODES) {
    int v = rp[i] + bsum[i >> 10];
    rp[i] = v;
    cur[i] = v;  // scatter cursor starts at row base
  }
  if (i == 0) rp[N_NODES] = N_EDGES;
  if (i < 8) ep[N_EDGES + i] = make_int2(0, 0);  // zero pad for predicated tail
}

// Bucketed scatter: destination region per bucket class stays L2-resident.
__global__ __launch_bounds__(256) void scatter_k(const int* __restrict__ row,
                                                 const int* __restrict__ col,
                                                 const float* __restrict__ val,
                                                 int* __restrict__ cur,
                                                 int2* __restrict__ ep) {
  const int bclass = blockIdx.x & (NBUCK - 1);
  const int chunk  = blockIdx.x >> 3;
  const int nchunk = gridDim.x >> 3;
  const int per = (N_EDGES + nchunk - 1) / nchunk;
  const int e0 = chunk * per;
  const int e1 = min(e0 + per, N_EDGES);
  for (int e = e0 + threadIdx.x; e < e1; e += 256) {
    int r = row[e];
    if ((r / BUCK_SZ) == bclass) {
      int p = atomicAdd(&cur[r], 1);
      ep[p] = make_int2(col[e], __float_as_int(val[e]));
    }
  }
}

// ---------------------------------------------------------------------------
// GEMM: H[N,K] @ W[K,COLS] -> S[N,64] bf16 (row stride fixed 64; cols >= COLS
// zero-filled so the 16-lane gather works for the 40-wide final layer too).
// Wave-per-8-rows; W column in VGPRs; H broadcast via readlane.
// ---------------------------------------------------------------------------
template <int K, int COLS>
__global__ __launch_bounds__(256) void gemm_rl(const float* __restrict__ H,
                                               const float* __restrict__ W,
                                               __hip_bfloat16* __restrict__ S) {
  const int lane = threadIdx.x & 63;
  constexpr int KW = K / 64;

  float wreg[K];
#pragma unroll
  for (int k = 0; k < K; ++k)
    wreg[k] = (COLS == 64 || lane < COLS) ? W[k * COLS + lane] : 0.0f;

  const int nrg = N_NODES / 8;  // 12500
  for (int rg = blockIdx.x * 4 + (threadIdx.x >> 6); rg < nrg; rg += gridDim.x * 4) {
    const int r0 = rg * 8;
    float hreg[8][KW];
#pragma unroll
    for (int i = 0; i < 8; ++i)
#pragma unroll
      for (int p = 0; p < KW; ++p)
        hreg[i][p] = H[(size_t)(r0 + i) * K + p * 64 + lane];

    float acc[8];
#pragma unroll
    for (int i = 0; i < 8; ++i) acc[i] = 0.0f;

#pragma unroll
    for (int p = 0; p < KW; ++p)
#pragma unroll
      for (int k = 0; k < 64; ++k) {
        const float w = wreg[p * 64 + k];
#pragma unroll
        for (int i = 0; i < 8; ++i)
          acc[i] = fmaf(rdlane(hreg[i][p], k), w, acc[i]);
      }

#pragma unroll
    for (int i = 0; i < 8; ++i)
      S[(size_t)(r0 + i) * 64 + lane] =
          __float2bfloat16((COLS == 64 || lane < COLS) ? acc[i] : 0.0f);
  }
}

// ---------------------------------------------------------------------------
// SpMM gather, 4-edges-per-load geometry. Wave per node. Lane = g*16 + i:
// group g (0..3) handles edges e+2g, e+2g+1; lane loads bf16x4 features
// 4i..4i+3 of the edge's row (16 lanes x 8 B = one 128 B row). One
// global_load_dwordx2 wave-instruction = 4 edge-rows gathered; 8 edges in
// flight per iteration. Fully predicated (ep has 8 zero-pad entries).
// Cross-group combine: 2x shfl_xor. Epilogue: bias+relu[+residual], fp32 out.
// ---------------------------------------------------------------------------
template <bool RES>
__global__ __launch_bounds__(256) void spmm16_k(
    const __hip_bfloat16* __restrict__ Sin, const int2* __restrict__ ep,
    const int* __restrict__ rp, const float* __restrict__ bias,
    const float* __restrict__ res, float* __restrict__ Hout) {
  const int lane = threadIdx.x & 63;
  const int g = lane >> 4;
  const int i16 = lane & 15;
  const int node = blockIdx.x * 4 + (threadIdx.x >> 6);
  const int start = rp[node], end = rp[node + 1];

  const unsigned short* S = (const unsigned short*)Sin;
  const int foff = i16 * 4;  // feature quad base

  float a0 = 0.0f, a1 = 0.0f, a2 = 0.0f, a3 = 0.0f;

  for (int e = start; e < end; e += 8) {
    const int e0 = e + 2 * g;
    int2 q0 = ep[e0];
    int2 q1 = ep[e0 + 1];
    float v0 = (e0 < end) ? __int_as_float(q0.y) : 0.0f;
    float v1 = (e0 + 1 < end) ? __int_as_float(q1.y) : 0.0f;
    ushort4 s0 = *(const ushort4*)(S + ((q0.x << 6) + foff));
    ushort4 s1 = *(const ushort4*)(S + ((q1.x << 6) + foff));
    a0 = fmaf(v0, bfbits(s0.x), a0);
    a1 = fmaf(v0, bfbits(s0.y), a1);
    a2 = fmaf(v0, bfbits(s0.z), a2);
    a3 = fmaf(v0, bfbits(s0.w), a3);
    a0 = fmaf(v1, bfbits(s1.x), a0);
    a1 = fmaf(v1, bfbits(s1.y), a1);
    a2 = fmaf(v1, bfbits(s1.z), a2);
    a3 = fmaf(v1, bfbits(s1.w), a3);
  }

  // combine the 4 edge-groups
  a0 += __shfl_xor(a0, 16); a0 += __shfl_xor(a0, 32);
  a1 += __shfl_xor(a1, 16); a1 += __shfl_xor(a1, 32);
  a2 += __shfl_xor(a2, 16); a2 += __shfl_xor(a2, 32);
  a3 += __shfl_xor(a3, 16); a3 += __shfl_xor(a3, 32);

  if (lane < 16) {
    float4 b4 = ((const float4*)bias)[lane];
    float h0 = fmaxf(a0 + b4.x, 0.0f);
    float h1 = fmaxf(a1 + b4.y, 0.0f);
    float h2 = fmaxf(a2 + b4.z, 0.0f);
    float h3 = fmaxf(a3 + b4.w, 0.0f);
    if (RES) {
      float4 r4 = ((const float4*)res)[node * 16 + lane];
      h0 += r4.x; h1 += r4.y; h2 += r4.z; h3 += r4.w;
    }
    ((float4*)Hout)[node * 16 + lane] = make_float4(h0, h1, h2, h3);
  }
}

// Final: same gather geometry on the 64-padded S40 (cols 40..63 are zeros),
// + bias + log_softmax (width-16 reductions; each group holds the full row).
__global__ __launch_bounds__(256) void spmm_final_k(
    const __hip_bfloat16* __restrict__ Sin, const int2* __restrict__ ep,
    const int* __restrict__ rp, const float* __restrict__ b2,
    float* __restrict__ out) {
  const int lane = threadIdx.x & 63;
  const int g = lane >> 4;
  const int i16 = lane & 15;
  const int node = blockIdx.x * 4 + (threadIdx.x >> 6);
  const int start = rp[node], end = rp[node + 1];

  const unsigned short* S = (const unsigned short*)Sin;
  const int foff = i16 * 4;

  float a0 = 0.0f, a1 = 0.0f, a2 = 0.0f, a3 = 0.0f;
  for (int e = start; e < end; e += 8) {
    const int e0 = e + 2 * g;
    int2 q0 = ep[e0];
    int2 q1 = ep[e0 + 1];
    float v0 = (e0 < end) ? __int_as_float(q0.y) : 0.0f;
    float v1 = (e0 + 1 < end) ? __int_as_float(q1.y) : 0.0f;
    ushort4 s0 = *(const ushort4*)(S + ((q0.x << 6) + foff));
    ushort4 s1 = *(const ushort4*)(S + ((q1.x << 6) + foff));
    a0 = fmaf(v0, bfbits(s0.x), a0);
    a1 = fmaf(v0, bfbits(s0.y), a1);
    a2 = fmaf(v0, bfbits(s0.z), a2);
    a3 = fmaf(v0, bfbits(s0.w), a3);
    a0 = fmaf(v1, bfbits(s1.x), a0);
    a1 = fmaf(v1, bfbits(s1.y), a1);
    a2 = fmaf(v1, bfbits(s1.z), a2);
    a3 = fmaf(v1, bfbits(s1.w), a3);
  }
  a0 += __shfl_xor(a0, 16); a0 += __shfl_xor(a0, 32);
  a1 += __shfl_xor(a1, 16); a1 += __shfl_xor(a1, 32);
  a2 += __shfl_xor(a2, 16); a2 += __shfl_xor(a2, 32);
  a3 += __shfl_xor(a3, 16); a3 += __shfl_xor(a3, 32);

  // logits for features 4*i16 .. 4*i16+3 (valid iff < 40; i16 < 10)
  const bool valid = (i16 < 10);
  float l0 = -INFINITY, l1 = -INFINITY, l2 = -INFINITY, l3 = -INFINITY;
  if (valid) {
    float4 b4 = ((const float4*)b2)[i16];
    l0 = a0 + b4.x; l1 = a1 + b4.y; l2 = a2 + b4.z; l3 = a3 + b4.w;
  }
  float mx = fmaxf(fmaxf(l0, l1), fmaxf(l2, l3));
#pragma unroll
  for (int off = 1; off < 16; off <<= 1) mx = fmaxf(mx, __shfl_xor(mx, off));
  float sum = valid ? (expf(l0 - mx) + expf(l1 - mx) + expf(l2 - mx) + expf(l3 - mx)) : 0.0f;
#pragma unroll
  for (int off = 1; off < 16; off <<= 1) sum += __shfl_xor(sum, off);
  if (lane < 10) {  // group 0 stores; 10 lanes x float4 = 40 floats
    float lg = logf(sum);
    ((float4*)out)[node * 10 + lane] =
        make_float4(l0 - mx - lg, l1 - mx - lg, l2 - mx - lg, l3 - mx - lg);
  }
}

// ---------------------------------------------------------------------------
extern "C" void kernel_launch(void* const* d_in, const int* in_sizes, int n_in,
                              void* d_out, int out_size, void* d_ws, size_t ws_size,
                              hipStream_t stream) {
  const float* x    = (const float*)d_in[0];
  const int*   erow = (const int*)d_in[1];
  const int*   ecol = (const int*)d_in[2];
  const float* eval = (const float*)d_in[3];
  const float* W1   = (const float*)d_in[4];
  const float* b1   = (const float*)d_in[5];
  const float* Wm   = (const float*)d_in[6];
  const float* bm   = (const float*)d_in[7];
  const float* W2   = (const float*)d_in[8];
  const float* b2   = (const float*)d_in[9];
  float* out = (float*)d_out;

  // Workspace layout (~78 MB)
  char* ws = (char*)d_ws;
  size_t off = 0;
  auto alloc = [&](size_t bytes) {
    void* p = ws + off;
    off = (off + bytes + 255) & ~(size_t)255;
    return p;
  };
  int*   rp   = (int*)alloc((N_NODES + 1) * sizeof(int));
  int*   cur  = (int*)alloc(N_NODES * sizeof(int));
  int*   bsum = (int*)alloc(128 * sizeof(int));
  int2*  ep   = (int2*)alloc((size_t)(N_EDGES + 8) * sizeof(int2));
  __hip_bfloat16* S = (__hip_bfloat16*)alloc((size_t)N_NODES * 64 * sizeof(__hip_bfloat16));
  float* H0 = (float*)alloc((size_t)N_NODES * 64 * sizeof(float));
  float* H1 = (float*)alloc((size_t)N_NODES * 64 * sizeof(float));

  const int ZB = (N_NODES + 255) / 256;   // 391
  const int EB = N_EDGES / 256;           // 6250 (exact)
  const int SB = (N_NODES + 1023) / 1024; // 98
  const int SCAT_B = NBUCK * 800;
  const int SPMM_GRID = N_NODES / 4;      // 25000 (exact)
  const int GEMM_GRID = 1024;

  // CSR build (same adjacency reused by all 8 layers)
  zero_cnt_k<<<ZB, 256, 0, stream>>>(cur);
  hist_k<<<EB, 256, 0, stream>>>(erow, cur);
  scan1_k<<<SB, 1024, 0, stream>>>(cur, rp, bsum);
  scan2_k<<<1, 64, 0, stream>>>(bsum, SB);
  scan3_k<<<ZB, 256, 0, stream>>>(rp, cur, bsum, ep);
  scatter_k<<<SCAT_B, 256, 0, stream>>>(erow, ecol, eval, cur, ep);

  // L1: S = x@W1 ; h1 = relu(A S + b1) -> H0
  gemm_rl<128, 64><<<GEMM_GRID, 256, 0, stream>>>(x, W1, S);
  spmm16_k<false><<<SPMM_GRID, 256, 0, stream>>>(S, ep, rp, b1, nullptr, H0);

  // L2: S = h1@Wm0 ; h2 = relu(A S + bm0) -> H1
  gemm_rl<64, 64><<<GEMM_GRID, 256, 0, stream>>>(H0, Wm, S);
  spmm16_k<false><<<SPMM_GRID, 256, 0, stream>>>(S, ep, rp, bm, nullptr, H1);

  // L3..L7 (Wm[1..5]): h = relu(A (prev@Wmk) + bmk) + prev2  (in-place on prev2)
  float* prev2 = H0;
  float* prev  = H1;
  for (int k = 1; k < NL; ++k) {
    gemm_rl<64, 64><<<GEMM_GRID, 256, 0, stream>>>(prev, Wm + (size_t)k * 4096, S);
    spmm16_k<true><<<SPMM_GRID, 256, 0, stream>>>(S, ep, rp, bm + k * 64, prev2, prev2);
    float* t = prev2; prev2 = prev; prev = t;
  }

  // Final: S(64-padded) = h7@W2 ; out = log_softmax(A S + b2)
  gemm_rl<64, 40><<<GEMM_GRID, 256, 0, stream>>>(prev, W2, S);
  spmm_final_k<<<SPMM_GRID, 256, 0, stream>>>(S, ep, rp, b2, out);
}

// Round 4
// 707.828 us; speedup vs baseline: 1.7844x; 1.2533x over previous
//
#include <hip/hip_runtime.h>
#include <hip/hip_bf16.h>
#include <math.h>

// Problem constants (fixed by the reference)
#define N_NODES 100000
#define N_EDGES 1600000
#define NFEAT 128
#define NHID  64
#define NCLASS 40
#define NL 6

#define NBUK 256          // coarse buckets for CSR build
#define RPB  391          // rows per bucket (391*256 >= 100000)
#define EPP  (N_EDGES / NBUK)  // 6250 edges per partition block (exact)
#define EP_PAD 256        // zero-padded ep tail for predicated spmm reads

__device__ __forceinline__ float bfbits(unsigned short u) {
  return __uint_as_float((unsigned int)u << 16);
}

// ---------------------------------------------------------------------------
// CSR build, full-line-write design.
// P0: per-partition-block 256-bucket histogram -> h2d[part][bucket]
// ---------------------------------------------------------------------------
__global__ __launch_bounds__(256) void p0_hist_k(const int* __restrict__ row,
                                                 int* __restrict__ h2d) {
  __shared__ int h[NBUK];
  const int i = blockIdx.x, t = threadIdx.x;
  h[t] = 0;
  __syncthreads();
  const int e0 = i * EPP, e1 = e0 + EPP;
  for (int e = e0 + t; e < e1; e += 256) atomicAdd(&h[row[e] / RPB], 1);
  __syncthreads();
  h2d[i * NBUK + t] = h[t];  // coalesced
}

// K1: per-bucket exclusive scan over partitions (in-place on h2d) + totals
__global__ __launch_bounds__(256) void k1_scanb_k(int* __restrict__ h2d,
                                                  int* __restrict__ btot) {
  __shared__ int sd[256];
  const int b = blockIdx.x, t = threadIdx.x;
  int v = h2d[t * NBUK + b];  // strided read (256 KB array, L2-resident)
  sd[t] = v;
  __syncthreads();
  for (int off = 1; off < 256; off <<= 1) {
    int a = (t >= off) ? sd[t - off] : 0;
    __syncthreads();
    sd[t] += a;
    __syncthreads();
  }
  h2d[t * NBUK + b] = sd[t] - v;  // exclusive prefix within bucket
  if (t == 255) btot[b] = sd[255];
}

// K2: exclusive scan of bucket totals -> bbase[257]; zero-pad ep tail
__global__ __launch_bounds__(256) void k2_scanbase_k(const int* __restrict__ btot,
                                                     int* __restrict__ bbase,
                                                     int2* __restrict__ ep) {
  __shared__ int sd[256];
  const int t = threadIdx.x;
  int v = btot[t];
  sd[t] = v;
  __syncthreads();
  for (int off = 1; off < 256; off <<= 1) {
    int a = (t >= off) ? sd[t - off] : 0;
    __syncthreads();
    sd[t] += a;
    __syncthreads();
  }
  bbase[t] = sd[t] - v;
  if (t == 255) bbase[256] = sd[255];  // == N_EDGES
  if (t < EP_PAD) ep[N_EDGES + t] = make_int2(0, 0);
}

// P2: partition edges into buckets. Each block's output sub-range per bucket
// is block-private (~50 KB total/block) -> lines fully covered before evict.
__global__ __launch_bounds__(256) void p2_part_k(
    const int* __restrict__ row, const int* __restrict__ col,
    const float* __restrict__ val, const int* __restrict__ h2d,
    const int* __restrict__ bbase, int2* __restrict__ pcv,
    unsigned short* __restrict__ plr) {
  __shared__ int cur[NBUK];
  const int i = blockIdx.x, t = threadIdx.x;
  cur[t] = bbase[t] + h2d[i * NBUK + t];  // coalesced
  __syncthreads();
  const int e0 = i * EPP, e1 = e0 + EPP;
  for (int e = e0 + t; e < e1; e += 256) {
    int r = row[e];
    int b = r / RPB;
    int p = atomicAdd(&cur[b], 1);
    pcv[p] = make_int2(col[e], __float_as_int(val[e]));
    plr[p] = (unsigned short)(r - b * RPB);
  }
}

// P3: per-bucket fine scatter. Local row ranks via LDS hist + wave scan;
// emits rp directly; ep writes confined to a block-private ~50 KB segment.
__global__ __launch_bounds__(256) void p3_fine_k(const int2* __restrict__ pcv,
                                                 const unsigned short* __restrict__ plr,
                                                 const int* __restrict__ bbase,
                                                 int* __restrict__ rp,
                                                 int2* __restrict__ ep) {
  __shared__ int cnt[RPB];
  __shared__ int cur[RPB];
  const int b = blockIdx.x, t = threadIdx.x;
  const int ebeg = bbase[b], eend = bbase[b + 1];
  const int r0 = b * RPB;
  const int nloc = min(RPB, N_NODES - r0);

  for (int i = t; i < RPB; i += 256) cnt[i] = 0;
  __syncthreads();
  for (int j = ebeg + t; j < eend; j += 256) atomicAdd(&cnt[plr[j]], 1);
  __syncthreads();

  // exclusive scan of cnt[0..390] by wave 0: lane L owns 7 slots
  if (t < 64) {
    const int base_ = t * 7;
    int v[7], s = 0;
#pragma unroll
    for (int k = 0; k < 7; ++k) {
      int idx = base_ + k;
      v[k] = (idx < RPB) ? cnt[idx] : 0;
      s += v[k];
    }
    int incl = s;
#pragma unroll
    for (int off = 1; off < 64; off <<= 1) {
      int y = __shfl_up(incl, off);
      if (t >= off) incl += y;
    }
    int run = incl - s;  // exclusive over lane sums
#pragma unroll
    for (int k = 0; k < 7; ++k) {
      int idx = base_ + k;
      if (idx < RPB) cnt[idx] = run;
      run += v[k];
    }
  }
  __syncthreads();

  for (int i = t; i < nloc; i += 256) {
    rp[r0 + i] = ebeg + cnt[i];
    cur[i] = cnt[i];
  }
  if (b == 0 && t == 0) rp[N_NODES] = N_EDGES;
  __syncthreads();

  for (int j = ebeg + t; j < eend; j += 256) {
    int lr = plr[j];
    int p = atomicAdd(&cur[lr], 1);
    ep[ebeg + p] = pcv[j];
  }
}

// ---------------------------------------------------------------------------
// GEMM: H[N,K] @ W[K,COLS] -> S[N,64] bf16 (row stride 64; cols >= COLS zero).
// ---------------------------------------------------------------------------
__device__ __forceinline__ float rdlane(float v, int l) {
  return __int_as_float(__builtin_amdgcn_readlane(__float_as_int(v), l));
}

template <int K, int COLS>
__global__ __launch_bounds__(256) void gemm_rl(const float* __restrict__ H,
                                               const float* __restrict__ W,
                                               __hip_bfloat16* __restrict__ S) {
  const int lane = threadIdx.x & 63;
  constexpr int KW = K / 64;

  float wreg[K];
#pragma unroll
  for (int k = 0; k < K; ++k)
    wreg[k] = (COLS == 64 || lane < COLS) ? W[k * COLS + lane] : 0.0f;

  const int nrg = N_NODES / 8;  // 12500
  for (int rg = blockIdx.x * 4 + (threadIdx.x >> 6); rg < nrg; rg += gridDim.x * 4) {
    const int r0 = rg * 8;
    float hreg[8][KW];
#pragma unroll
    for (int i = 0; i < 8; ++i)
#pragma unroll
      for (int p = 0; p < KW; ++p)
        hreg[i][p] = H[(size_t)(r0 + i) * K + p * 64 + lane];

    float acc[8];
#pragma unroll
    for (int i = 0; i < 8; ++i) acc[i] = 0.0f;

#pragma unroll
    for (int p = 0; p < KW; ++p)
#pragma unroll
      for (int k = 0; k < 64; ++k) {
        const float w = wreg[p * 64 + k];
#pragma unroll
        for (int i = 0; i < 8; ++i)
          acc[i] = fmaf(rdlane(hreg[i][p], k), w, acc[i]);
      }

#pragma unroll
    for (int i = 0; i < 8; ++i)
      S[(size_t)(r0 + i) * 64 + lane] =
          __float2bfloat16((COLS == 64 || lane < COLS) ? acc[i] : 0.0f);
  }
}

// ---------------------------------------------------------------------------
// SpMM: wave per NODE PAIR. Groups 0-1 -> node A, groups 2-3 -> node B.
// Per iteration each node processes 8 edges -> 4 ep loads + 4 row gathers in
// flight per wave (2x the R3 MLP). 16-lane group reads one 128 B bf16 row.
// Combine groups via one shfl_xor(16). Epilogue: bias+relu[+res], fp32 out.
// ---------------------------------------------------------------------------
template <bool RES>
__global__ __launch_bounds__(256) void spmm16_k(
    const __hip_bfloat16* __restrict__ Sin, const int2* __restrict__ ep,
    const int* __restrict__ rp, const float* __restrict__ bias,
    const float* __restrict__ res, float* __restrict__ Hout) {
  const int lane = threadIdx.x & 63;
  const int g = lane >> 4;
  const int i16 = lane & 15;
  const int gl = g & 1;
  const int pair = blockIdx.x * 4 + (threadIdx.x >> 6);
  const int nodeA = pair * 2;
  const int sA = rp[nodeA], sB = rp[nodeA + 1], eB = rp[nodeA + 2];
  const bool isB = (g >= 2);
  const int myNode = nodeA + (isB ? 1 : 0);
  const int myEnd = isB ? eB : sB;
  const int iters = (max(sB - sA, eB - sB) + 7) >> 3;

  const unsigned short* S = (const unsigned short*)Sin;
  const int foff = i16 * 4;

  float a0 = 0.0f, a1 = 0.0f, a2 = 0.0f, a3 = 0.0f;
  int e = (isB ? sB : sA) + gl * 2;
  for (int it = 0; it < iters; ++it, e += 8) {
    const int o0 = e, o1 = e + 1, o2 = e + 4, o3 = e + 5;
    int2 q0 = ep[o0];
    int2 q1 = ep[o1];
    int2 q2 = ep[o2];
    int2 q3 = ep[o3];
    float v0 = (o0 < myEnd) ? __int_as_float(q0.y) : 0.0f;
    float v1 = (o1 < myEnd) ? __int_as_float(q1.y) : 0.0f;
    float v2 = (o2 < myEnd) ? __int_as_float(q2.y) : 0.0f;
    float v3 = (o3 < myEnd) ? __int_as_float(q3.y) : 0.0f;
    ushort4 s0 = *(const ushort4*)(S + ((q0.x << 6) + foff));
    ushort4 s1 = *(const ushort4*)(S + ((q1.x << 6) + foff));
    ushort4 s2 = *(const ushort4*)(S + ((q2.x << 6) + foff));
    ushort4 s3 = *(const ushort4*)(S + ((q3.x << 6) + foff));
    a0 = fmaf(v0, bfbits(s0.x), a0); a1 = fmaf(v0, bfbits(s0.y), a1);
    a2 = fmaf(v0, bfbits(s0.z), a2); a3 = fmaf(v0, bfbits(s0.w), a3);
    a0 = fmaf(v1, bfbits(s1.x), a0); a1 = fmaf(v1, bfbits(s1.y), a1);
    a2 = fmaf(v1, bfbits(s1.z), a2); a3 = fmaf(v1, bfbits(s1.w), a3);
    a0 = fmaf(v2, bfbits(s2.x), a0); a1 = fmaf(v2, bfbits(s2.y), a1);
    a2 = fmaf(v2, bfbits(s2.z), a2); a3 = fmaf(v2, bfbits(s2.w), a3);
    a0 = fmaf(v3, bfbits(s3.x), a0); a1 = fmaf(v3, bfbits(s3.y), a1);
    a2 = fmaf(v3, bfbits(s3.z), a2); a3 = fmaf(v3, bfbits(s3.w), a3);
  }

  // combine the two groups of each node (g0+g1 -> lanes 0-15; g2+g3 -> 32-47)
  a0 += __shfl_xor(a0, 16);
  a1 += __shfl_xor(a1, 16);
  a2 += __shfl_xor(a2, 16);
  a3 += __shfl_xor(a3, 16);

  if ((g & 1) == 0) {  // g==0 (node A) or g==2 (node B)
    float4 b4 = ((const float4*)bias)[i16];
    float h0 = fmaxf(a0 + b4.x, 0.0f);
    float h1 = fmaxf(a1 + b4.y, 0.0f);
    float h2 = fmaxf(a2 + b4.z, 0.0f);
    float h3 = fmaxf(a3 + b4.w, 0.0f);
    if (RES) {
      float4 r4 = ((const float4*)res)[myNode * 16 + i16];
      h0 += r4.x; h1 += r4.y; h2 += r4.z; h3 += r4.w;
    }
    ((float4*)Hout)[myNode * 16 + i16] = make_float4(h0, h1, h2, h3);
  }
}

// Final: same pair geometry on 64-padded S40 + bias + log_softmax.
__global__ __launch_bounds__(256) void spmm_final_k(
    const __hip_bfloat16* __restrict__ Sin, const int2* __restrict__ ep,
    const int* __restrict__ rp, const float* __restrict__ b2,
    float* __restrict__ out) {
  const int lane = threadIdx.x & 63;
  const int g = lane >> 4;
  const int i16 = lane & 15;
  const int gl = g & 1;
  const int pair = blockIdx.x * 4 + (threadIdx.x >> 6);
  const int nodeA = pair * 2;
  const int sA = rp[nodeA], sB = rp[nodeA + 1], eB = rp[nodeA + 2];
  const bool isB = (g >= 2);
  const int myNode = nodeA + (isB ? 1 : 0);
  const int myEnd = isB ? eB : sB;
  const int iters = (max(sB - sA, eB - sB) + 7) >> 3;

  const unsigned short* S = (const unsigned short*)Sin;
  const int foff = i16 * 4;

  float a0 = 0.0f, a1 = 0.0f, a2 = 0.0f, a3 = 0.0f;
  int e = (isB ? sB : sA) + gl * 2;
  for (int it = 0; it < iters; ++it, e += 8) {
    const int o0 = e, o1 = e + 1, o2 = e + 4, o3 = e + 5;
    int2 q0 = ep[o0];
    int2 q1 = ep[o1];
    int2 q2 = ep[o2];
    int2 q3 = ep[o3];
    float v0 = (o0 < myEnd) ? __int_as_float(q0.y) : 0.0f;
    float v1 = (o1 < myEnd) ? __int_as_float(q1.y) : 0.0f;
    float v2 = (o2 < myEnd) ? __int_as_float(q2.y) : 0.0f;
    float v3 = (o3 < myEnd) ? __int_as_float(q3.y) : 0.0f;
    ushort4 s0 = *(const ushort4*)(S + ((q0.x << 6) + foff));
    ushort4 s1 = *(const ushort4*)(S + ((q1.x << 6) + foff));
    ushort4 s2 = *(const ushort4*)(S + ((q2.x << 6) + foff));
    ushort4 s3 = *(const ushort4*)(S + ((q3.x << 6) + foff));
    a0 = fmaf(v0, bfbits(s0.x), a0); a1 = fmaf(v0, bfbits(s0.y), a1);
    a2 = fmaf(v0, bfbits(s0.z), a2); a3 = fmaf(v0, bfbits(s0.w), a3);
    a0 = fmaf(v1, bfbits(s1.x), a0); a1 = fmaf(v1, bfbits(s1.y), a1);
    a2 = fmaf(v1, bfbits(s1.z), a2); a3 = fmaf(v1, bfbits(s1.w), a3);
    a0 = fmaf(v2, bfbits(s2.x), a0); a1 = fmaf(v2, bfbits(s2.y), a1);
    a2 = fmaf(v2, bfbits(s2.z), a2); a3 = fmaf(v2, bfbits(s2.w), a3);
    a0 = fmaf(v3, bfbits(s3.x), a0); a1 = fmaf(v3, bfbits(s3.y), a1);
    a2 = fmaf(v3, bfbits(s3.z), a2); a3 = fmaf(v3, bfbits(s3.w), a3);
  }
  a0 += __shfl_xor(a0, 16);
  a1 += __shfl_xor(a1, 16);
  a2 += __shfl_xor(a2, 16);
  a3 += __shfl_xor(a3, 16);

  // lanes 0-15 hold node A's full row; lanes 32-47 node B's. Softmax width 16.
  const bool valid = (i16 < 10);  // 10 quads = 40 classes
  float l0 = -INFINITY, l1 = -INFINITY, l2 = -INFINITY, l3 = -INFINITY;
  if (valid) {
    float4 b4 = ((const float4*)b2)[i16];
    l0 = a0 + b4.x; l1 = a1 + b4.y; l2 = a2 + b4.z; l3 = a3 + b4.w;
  }
  float mx = fmaxf(fmaxf(l0, l1), fmaxf(l2, l3));
#pragma unroll
  for (int off = 1; off < 16; off <<= 1) mx = fmaxf(mx, __shfl_xor(mx, off));
  float sum = valid ? (expf(l0 - mx) + expf(l1 - mx) + expf(l2 - mx) + expf(l3 - mx)) : 0.0f;
#pragma unroll
  for (int off = 1; off < 16; off <<= 1) sum += __shfl_xor(sum, off);
  if (((g & 1) == 0) && valid) {
    float lg = logf(sum);
    ((float4*)out)[myNode * 10 + i16] =
        make_float4(l0 - mx - lg, l1 - mx - lg, l2 - mx - lg, l3 - mx - lg);
  }
}

// ---------------------------------------------------------------------------
extern "C" void kernel_launch(void* const* d_in, const int* in_sizes, int n_in,
                              void* d_out, int out_size, void* d_ws, size_t ws_size,
                              hipStream_t stream) {
  const float* x    = (const float*)d_in[0];
  const int*   erow = (const int*)d_in[1];
  const int*   ecol = (const int*)d_in[2];
  const float* eval = (const float*)d_in[3];
  const float* W1   = (const float*)d_in[4];
  const float* b1   = (const float*)d_in[5];
  const float* Wm   = (const float*)d_in[6];
  const float* bm   = (const float*)d_in[7];
  const float* W2   = (const float*)d_in[8];
  const float* b2   = (const float*)d_in[9];
  float* out = (float*)d_out;

  // Workspace (~81 MB). pcv/plr are dead after p3_fine_k, so S aliases them.
  char* ws = (char*)d_ws;
  size_t off = 0;
  auto alloc = [&](size_t bytes) {
    void* p = ws + off;
    off = (off + bytes + 255) & ~(size_t)255;
    return p;
  };
  int*  rp    = (int*)alloc((N_NODES + 1) * sizeof(int));
  int*  h2d   = (int*)alloc((size_t)NBUK * NBUK * sizeof(int));
  int*  btot  = (int*)alloc(NBUK * sizeof(int));
  int*  bbase = (int*)alloc((NBUK + 1) * sizeof(int));
  int2* ep    = (int2*)alloc((size_t)(N_EDGES + EP_PAD) * sizeof(int2));
  char* U     = (char*)alloc((size_t)N_EDGES * sizeof(int2) +
                             (((size_t)N_EDGES * sizeof(unsigned short) + 255) & ~(size_t)255));
  int2* pcv = (int2*)U;
  unsigned short* plr = (unsigned short*)(U + (size_t)N_EDGES * sizeof(int2));
  __hip_bfloat16* S = (__hip_bfloat16*)U;  // alias: live only after CSR build
  float* H0 = (float*)alloc((size_t)N_NODES * 64 * sizeof(float));
  float* H1 = (float*)alloc((size_t)N_NODES * 64 * sizeof(float));

  const int SPMM_GRID = N_NODES / 8;  // 12500 blocks x 4 waves x 2 nodes
  const int GEMM_GRID = 1024;

  // CSR build
  p0_hist_k<<<NBUK, 256, 0, stream>>>(erow, h2d);
  k1_scanb_k<<<NBUK, 256, 0, stream>>>(h2d, btot);
  k2_scanbase_k<<<1, 256, 0, stream>>>(btot, bbase, ep);
  p2_part_k<<<NBUK, 256, 0, stream>>>(erow, ecol, eval, h2d, bbase, pcv, plr);
  p3_fine_k<<<NBUK, 256, 0, stream>>>(pcv, plr, bbase, rp, ep);

  // L1: S = x@W1 ; h1 = relu(A S + b1) -> H0
  gemm_rl<128, 64><<<GEMM_GRID, 256, 0, stream>>>(x, W1, S);
  spmm16_k<false><<<SPMM_GRID, 256, 0, stream>>>(S, ep, rp, b1, nullptr, H0);

  // L2: S = h1@Wm0 ; h2 = relu(A S + bm0) -> H1
  gemm_rl<64, 64><<<GEMM_GRID, 256, 0, stream>>>(H0, Wm, S);
  spmm16_k<false><<<SPMM_GRID, 256, 0, stream>>>(S, ep, rp, bm, nullptr, H1);

  // L3..L7 (Wm[1..5]): h = relu(A (prev@Wmk) + bmk) + prev2  (in-place)
  float* prev2 = H0;
  float* prev  = H1;
  for (int k = 1; k < NL; ++k) {
    gemm_rl<64, 64><<<GEMM_GRID, 256, 0, stream>>>(prev, Wm + (size_t)k * 4096, S);
    spmm16_k<true><<<SPMM_GRID, 256, 0, stream>>>(S, ep, rp, bm + k * 64, prev2, prev2);
    float* t = prev2; prev2 = prev; prev = t;
  }

  // Final: S(64-padded) = h7@W2 ; out = log_softmax(A S + b2)
  gemm_rl<64, 40><<<GEMM_GRID, 256, 0, stream>>>(prev, W2, S);
  spmm_final_k<<<SPMM_GRID, 256, 0, stream>>>(S, ep, rp, b2, out);
}

// Round 5
// 554.430 us; speedup vs baseline: 2.2780x; 1.2767x over previous
//
#include <hip/hip_runtime.h>
#include <hip/hip_bf16.h>
#include <math.h>

// Problem constants (fixed by the reference)
#define N_NODES 100000
#define N_EDGES 1600000
#define NFEAT 128
#define NHID  64
#define NCLASS 40
#define NL 6

#define NBUK 256          // coarse buckets for CSR build
#define RPB  391          // rows per bucket (391*256 >= 100000)
#define EPP  (N_EDGES / NBUK)  // 6250 edges per partition block (exact)
#define EP_PAD 256        // zero-padded ep tail for predicated spmm reads

typedef __attribute__((ext_vector_type(8))) short short8;
typedef __attribute__((ext_vector_type(4))) float floatx4;

__device__ __forceinline__ float bfbits(unsigned short u) {
  return __uint_as_float((unsigned int)u << 16);
}
__device__ __forceinline__ short f2bs(float f) {
  __hip_bfloat16 h = __float2bfloat16(f);  // RNE
  return *reinterpret_cast<short*>(&h);
}

// ---------------------------------------------------------------------------
// CSR build (R4 design, full-line writes — measured ~30 us total)
// ---------------------------------------------------------------------------
__global__ __launch_bounds__(256) void p0_hist_k(const int* __restrict__ row,
                                                 int* __restrict__ h2d) {
  __shared__ int h[NBUK];
  const int i = blockIdx.x, t = threadIdx.x;
  h[t] = 0;
  __syncthreads();
  const int e0 = i * EPP, e1 = e0 + EPP;
  for (int e = e0 + t; e < e1; e += 256) atomicAdd(&h[row[e] / RPB], 1);
  __syncthreads();
  h2d[i * NBUK + t] = h[t];  // coalesced
}

__global__ __launch_bounds__(256) void k1_scanb_k(int* __restrict__ h2d,
                                                  int* __restrict__ btot) {
  __shared__ int sd[256];
  const int b = blockIdx.x, t = threadIdx.x;
  int v = h2d[t * NBUK + b];
  sd[t] = v;
  __syncthreads();
  for (int off = 1; off < 256; off <<= 1) {
    int a = (t >= off) ? sd[t - off] : 0;
    __syncthreads();
    sd[t] += a;
    __syncthreads();
  }
  h2d[t * NBUK + b] = sd[t] - v;  // exclusive prefix within bucket
  if (t == 255) btot[b] = sd[255];
}

__global__ __launch_bounds__(256) void k2_scanbase_k(const int* __restrict__ btot,
                                                     int* __restrict__ bbase,
                                                     int2* __restrict__ ep) {
  __shared__ int sd[256];
  const int t = threadIdx.x;
  int v = btot[t];
  sd[t] = v;
  __syncthreads();
  for (int off = 1; off < 256; off <<= 1) {
    int a = (t >= off) ? sd[t - off] : 0;
    __syncthreads();
    sd[t] += a;
    __syncthreads();
  }
  bbase[t] = sd[t] - v;
  if (t == 255) bbase[256] = sd[255];  // == N_EDGES
  if (t < EP_PAD) ep[N_EDGES + t] = make_int2(0, 0);
}

__global__ __launch_bounds__(256) void p2_part_k(
    const int* __restrict__ row, const int* __restrict__ col,
    const float* __restrict__ val, const int* __restrict__ h2d,
    const int* __restrict__ bbase, int2* __restrict__ pcv,
    unsigned short* __restrict__ plr) {
  __shared__ int cur[NBUK];
  const int i = blockIdx.x, t = threadIdx.x;
  cur[t] = bbase[t] + h2d[i * NBUK + t];
  __syncthreads();
  const int e0 = i * EPP, e1 = e0 + EPP;
  for (int e = e0 + t; e < e1; e += 256) {
    int r = row[e];
    int b = r / RPB;
    int p = atomicAdd(&cur[b], 1);
    pcv[p] = make_int2(col[e], __float_as_int(val[e]));
    plr[p] = (unsigned short)(r - b * RPB);
  }
}

__global__ __launch_bounds__(256) void p3_fine_k(const int2* __restrict__ pcv,
                                                 const unsigned short* __restrict__ plr,
                                                 const int* __restrict__ bbase,
                                                 int* __restrict__ rp,
                                                 int2* __restrict__ ep) {
  __shared__ int cnt[RPB];
  __shared__ int cur[RPB];
  const int b = blockIdx.x, t = threadIdx.x;
  const int ebeg = bbase[b], eend = bbase[b + 1];
  const int r0 = b * RPB;
  const int nloc = min(RPB, N_NODES - r0);

  for (int i = t; i < RPB; i += 256) cnt[i] = 0;
  __syncthreads();
  for (int j = ebeg + t; j < eend; j += 256) atomicAdd(&cnt[plr[j]], 1);
  __syncthreads();

  if (t < 64) {  // exclusive scan of cnt[0..390] by wave 0
    const int base_ = t * 7;
    int v[7], s = 0;
#pragma unroll
    for (int k = 0; k < 7; ++k) {
      int idx = base_ + k;
      v[k] = (idx < RPB) ? cnt[idx] : 0;
      s += v[k];
    }
    int incl = s;
#pragma unroll
    for (int off = 1; off < 64; off <<= 1) {
      int y = __shfl_up(incl, off);
      if (t >= off) incl += y;
    }
    int run = incl - s;
#pragma unroll
    for (int k = 0; k < 7; ++k) {
      int idx = base_ + k;
      if (idx < RPB) cnt[idx] = run;
      run += v[k];
    }
  }
  __syncthreads();

  for (int i = t; i < nloc; i += 256) {
    rp[r0 + i] = ebeg + cnt[i];
    cur[i] = cnt[i];
  }
  if (b == 0 && t == 0) rp[N_NODES] = N_EDGES;
  __syncthreads();

  for (int j = ebeg + t; j < eend; j += 256) {
    int lr = plr[j];
    int p = atomicAdd(&cur[lr], 1);
    ep[ebeg + p] = pcv[j];
  }
}

// ---------------------------------------------------------------------------
// MFMA GEMM: S[N,64](bf16) = H[N,K](fp32, rounded to bf16) @ W[K,COLS](fp32).
// Wave computes a 16-row x 64-col tile via 4 col-tiles x (K/32) mfma steps.
// Layouts (gfx950, 16x16x32_bf16): A[m=lane&15][k=quad*8+j],
// B[k=quad*8+j][n=lane&15], C/D col=lane&15, row=quad*4+reg (m89/m120).
// Cols >= COLS are zero-filled (B frag zeroed) for the 40-wide final layer.
// ---------------------------------------------------------------------------
template <int K, int COLS>
__global__ __launch_bounds__(256) void gemm_mfma(const float* __restrict__ H,
                                                 const float* __restrict__ W,
                                                 __hip_bfloat16* __restrict__ S) {
  constexpr int NK = K / 32;
  const int lane = threadIdx.x & 63;
  const int quad = lane >> 4;
  const int m = lane & 15;

  // Preload B fragments (W is tiny; L2-resident, reused by every wave)
  short8 bf[4][NK];
#pragma unroll
  for (int t = 0; t < 4; ++t) {
    const int cc = t * 16 + m;
#pragma unroll
    for (int h = 0; h < NK; ++h) {
#pragma unroll
      for (int j = 0; j < 8; ++j) {
        const int kk = h * 32 + quad * 8 + j;
        bf[t][h][j] = (COLS == 64 || cc < COLS) ? f2bs(W[kk * COLS + cc]) : (short)0;
      }
    }
  }

  const int r0 = blockIdx.x * 64 + (threadIdx.x >> 6) * 16;
  if (r0 >= N_NODES) return;
  const int arow = min(r0 + m, N_NODES - 1);  // clamp A loads for tail block

  // A fragments: lane reads 8 consecutive k of its row per mfma step
  short8 af[NK];
#pragma unroll
  for (int h = 0; h < NK; ++h) {
    const float* hp = H + (size_t)arow * K + h * 32 + quad * 8;
    float4 p0 = *(const float4*)hp;
    float4 p1 = *(const float4*)(hp + 4);
    af[h][0] = f2bs(p0.x); af[h][1] = f2bs(p0.y);
    af[h][2] = f2bs(p0.z); af[h][3] = f2bs(p0.w);
    af[h][4] = f2bs(p1.x); af[h][5] = f2bs(p1.y);
    af[h][6] = f2bs(p1.z); af[h][7] = f2bs(p1.w);
  }

  floatx4 acc[4];
#pragma unroll
  for (int t = 0; t < 4; ++t) {
    acc[t] = {0.0f, 0.0f, 0.0f, 0.0f};
#pragma unroll
    for (int h = 0; h < NK; ++h)
      acc[t] = __builtin_amdgcn_mfma_f32_16x16x32_bf16(af[h], bf[t][h], acc[t], 0, 0, 0);
  }

  unsigned short* Sp = (unsigned short*)S;
#pragma unroll
  for (int t = 0; t < 4; ++t) {
#pragma unroll
    for (int r = 0; r < 4; ++r) {
      const int row = r0 + quad * 4 + r;
      if (row < N_NODES)
        Sp[(size_t)row * 64 + t * 16 + m] = (unsigned short)f2bs(acc[t][r]);
    }
  }
}

// ---------------------------------------------------------------------------
// SpMM: wave per NODE PAIR (R4 design, measured ~25 us). Groups 0-1 -> node A,
// groups 2-3 -> node B; 8 edges/node/iter; 16-lane group reads one 128 B row.
// ---------------------------------------------------------------------------
template <bool RES>
__global__ __launch_bounds__(256) void spmm16_k(
    const __hip_bfloat16* __restrict__ Sin, const int2* __restrict__ ep,
    const int* __restrict__ rp, const float* __restrict__ bias,
    const float* __restrict__ res, float* __restrict__ Hout) {
  const int lane = threadIdx.x & 63;
  const int g = lane >> 4;
  const int i16 = lane & 15;
  const int gl = g & 1;
  const int pair = blockIdx.x * 4 + (threadIdx.x >> 6);
  const int nodeA = pair * 2;
  const int sA = rp[nodeA], sB = rp[nodeA + 1], eB = rp[nodeA + 2];
  const bool isB = (g >= 2);
  const int myNode = nodeA + (isB ? 1 : 0);
  const int myEnd = isB ? eB : sB;
  const int iters = (max(sB - sA, eB - sB) + 7) >> 3;

  const unsigned short* S = (const unsigned short*)Sin;
  const int foff = i16 * 4;

  float a0 = 0.0f, a1 = 0.0f, a2 = 0.0f, a3 = 0.0f;
  int e = (isB ? sB : sA) + gl * 2;
  for (int it = 0; it < iters; ++it, e += 8) {
    const int o0 = e, o1 = e + 1, o2 = e + 4, o3 = e + 5;
    int2 q0 = ep[o0];
    int2 q1 = ep[o1];
    int2 q2 = ep[o2];
    int2 q3 = ep[o3];
    float v0 = (o0 < myEnd) ? __int_as_float(q0.y) : 0.0f;
    float v1 = (o1 < myEnd) ? __int_as_float(q1.y) : 0.0f;
    float v2 = (o2 < myEnd) ? __int_as_float(q2.y) : 0.0f;
    float v3 = (o3 < myEnd) ? __int_as_float(q3.y) : 0.0f;
    ushort4 s0 = *(const ushort4*)(S + ((q0.x << 6) + foff));
    ushort4 s1 = *(const ushort4*)(S + ((q1.x << 6) + foff));
    ushort4 s2 = *(const ushort4*)(S + ((q2.x << 6) + foff));
    ushort4 s3 = *(const ushort4*)(S + ((q3.x << 6) + foff));
    a0 = fmaf(v0, bfbits(s0.x), a0); a1 = fmaf(v0, bfbits(s0.y), a1);
    a2 = fmaf(v0, bfbits(s0.z), a2); a3 = fmaf(v0, bfbits(s0.w), a3);
    a0 = fmaf(v1, bfbits(s1.x), a0); a1 = fmaf(v1, bfbits(s1.y), a1);
    a2 = fmaf(v1, bfbits(s1.z), a2); a3 = fmaf(v1, bfbits(s1.w), a3);
    a0 = fmaf(v2, bfbits(s2.x), a0); a1 = fmaf(v2, bfbits(s2.y), a1);
    a2 = fmaf(v2, bfbits(s2.z), a2); a3 = fmaf(v2, bfbits(s2.w), a3);
    a0 = fmaf(v3, bfbits(s3.x), a0); a1 = fmaf(v3, bfbits(s3.y), a1);
    a2 = fmaf(v3, bfbits(s3.z), a2); a3 = fmaf(v3, bfbits(s3.w), a3);
  }

  a0 += __shfl_xor(a0, 16);
  a1 += __shfl_xor(a1, 16);
  a2 += __shfl_xor(a2, 16);
  a3 += __shfl_xor(a3, 16);

  if ((g & 1) == 0) {  // g==0 (node A) or g==2 (node B)
    float4 b4 = ((const float4*)bias)[i16];
    float h0 = fmaxf(a0 + b4.x, 0.0f);
    float h1 = fmaxf(a1 + b4.y, 0.0f);
    float h2 = fmaxf(a2 + b4.z, 0.0f);
    float h3 = fmaxf(a3 + b4.w, 0.0f);
    if (RES) {
      float4 r4 = ((const float4*)res)[myNode * 16 + i16];
      h0 += r4.x; h1 += r4.y; h2 += r4.z; h3 += r4.w;
    }
    ((float4*)Hout)[myNode * 16 + i16] = make_float4(h0, h1, h2, h3);
  }
}

// Final: same pair geometry on 64-padded S40 + bias + log_softmax.
__global__ __launch_bounds__(256) void spmm_final_k(
    const __hip_bfloat16* __restrict__ Sin, const int2* __restrict__ ep,
    const int* __restrict__ rp, const float* __restrict__ b2,
    float* __restrict__ out) {
  const int lane = threadIdx.x & 63;
  const int g = lane >> 4;
  const int i16 = lane & 15;
  const int gl = g & 1;
  const int pair = blockIdx.x * 4 + (threadIdx.x >> 6);
  const int nodeA = pair * 2;
  const int sA = rp[nodeA], sB = rp[nodeA + 1], eB = rp[nodeA + 2];
  const bool isB = (g >= 2);
  const int myNode = nodeA + (isB ? 1 : 0);
  const int myEnd = isB ? eB : sB;
  const int iters = (max(sB - sA, eB - sB) + 7) >> 3;

  const unsigned short* S = (const unsigned short*)Sin;
  const int foff = i16 * 4;

  float a0 = 0.0f, a1 = 0.0f, a2 = 0.0f, a3 = 0.0f;
  int e = (isB ? sB : sA) + gl * 2;
  for (int it = 0; it < iters; ++it, e += 8) {
    const int o0 = e, o1 = e + 1, o2 = e + 4, o3 = e + 5;
    int2 q0 = ep[o0];
    int2 q1 = ep[o1];
    int2 q2 = ep[o2];
    int2 q3 = ep[o3];
    float v0 = (o0 < myEnd) ? __int_as_float(q0.y) : 0.0f;
    float v1 = (o1 < myEnd) ? __int_as_float(q1.y) : 0.0f;
    float v2 = (o2 < myEnd) ? __int_as_float(q2.y) : 0.0f;
    float v3 = (o3 < myEnd) ? __int_as_float(q3.y) : 0.0f;
    ushort4 s0 = *(const ushort4*)(S + ((q0.x << 6) + foff));
    ushort4 s1 = *(const ushort4*)(S + ((q1.x << 6) + foff));
    ushort4 s2 = *(const ushort4*)(S + ((q2.x << 6) + foff));
    ushort4 s3 = *(const ushort4*)(S + ((q3.x << 6) + foff));
    a0 = fmaf(v0, bfbits(s0.x), a0); a1 = fmaf(v0, bfbits(s0.y), a1);
    a2 = fmaf(v0, bfbits(s0.z), a2); a3 = fmaf(v0, bfbits(s0.w), a3);
    a0 = fmaf(v1, bfbits(s1.x), a0); a1 = fmaf(v1, bfbits(s1.y), a1);
    a2 = fmaf(v1, bfbits(s1.z), a2); a3 = fmaf(v1, bfbits(s1.w), a3);
    a0 = fmaf(v2, bfbits(s2.x), a0); a1 = fmaf(v2, bfbits(s2.y), a1);
    a2 = fmaf(v2, bfbits(s2.z), a2); a3 = fmaf(v2, bfbits(s2.w), a3);
    a0 = fmaf(v3, bfbits(s3.x), a0); a1 = fmaf(v3, bfbits(s3.y), a1);
    a2 = fmaf(v3, bfbits(s3.z), a2); a3 = fmaf(v3, bfbits(s3.w), a3);
  }
  a0 += __shfl_xor(a0, 16);
  a1 += __shfl_xor(a1, 16);
  a2 += __shfl_xor(a2, 16);
  a3 += __shfl_xor(a3, 16);

  const bool valid = (i16 < 10);  // 10 quads = 40 classes
  float l0 = -INFINITY, l1 = -INFINITY, l2 = -INFINITY, l3 = -INFINITY;
  if (valid) {
    float4 b4 = ((const float4*)b2)[i16];
    l0 = a0 + b4.x; l1 = a1 + b4.y; l2 = a2 + b4.z; l3 = a3 + b4.w;
  }
  float mx = fmaxf(fmaxf(l0, l1), fmaxf(l2, l3));
#pragma unroll
  for (int off = 1; off < 16; off <<= 1) mx = fmaxf(mx, __shfl_xor(mx, off));
  float sum = valid ? (expf(l0 - mx) + expf(l1 - mx) + expf(l2 - mx) + expf(l3 - mx)) : 0.0f;
#pragma unroll
  for (int off = 1; off < 16; off <<= 1) sum += __shfl_xor(sum, off);
  if (((g & 1) == 0) && valid) {
    float lg = logf(sum);
    ((float4*)out)[myNode * 10 + i16] =
        make_float4(l0 - mx - lg, l1 - mx - lg, l2 - mx - lg, l3 - mx - lg);
  }
}

// ---------------------------------------------------------------------------
extern "C" void kernel_launch(void* const* d_in, const int* in_sizes, int n_in,
                              void* d_out, int out_size, void* d_ws, size_t ws_size,
                              hipStream_t stream) {
  const float* x    = (const float*)d_in[0];
  const int*   erow = (const int*)d_in[1];
  const int*   ecol = (const int*)d_in[2];
  const float* eval = (const float*)d_in[3];
  const float* W1   = (const float*)d_in[4];
  const float* b1   = (const float*)d_in[5];
  const float* Wm   = (const float*)d_in[6];
  const float* bm   = (const float*)d_in[7];
  const float* W2   = (const float*)d_in[8];
  const float* b2   = (const float*)d_in[9];
  float* out = (float*)d_out;

  // Workspace (~81 MB). pcv/plr dead after p3_fine_k -> S aliases them.
  char* ws = (char*)d_ws;
  size_t off = 0;
  auto alloc = [&](size_t bytes) {
    void* p = ws + off;
    off = (off + bytes + 255) & ~(size_t)255;
    return p;
  };
  int*  rp    = (int*)alloc((N_NODES + 1) * sizeof(int));
  int*  h2d   = (int*)alloc((size_t)NBUK * NBUK * sizeof(int));
  int*  btot  = (int*)alloc(NBUK * sizeof(int));
  int*  bbase = (int*)alloc((NBUK + 1) * sizeof(int));
  int2* ep    = (int2*)alloc((size_t)(N_EDGES + EP_PAD) * sizeof(int2));
  char* U     = (char*)alloc((size_t)N_EDGES * sizeof(int2) +
                             (((size_t)N_EDGES * sizeof(unsigned short) + 255) & ~(size_t)255));
  int2* pcv = (int2*)U;
  unsigned short* plr = (unsigned short*)(U + (size_t)N_EDGES * sizeof(int2));
  __hip_bfloat16* S = (__hip_bfloat16*)U;  // alias: live only after CSR build
  float* H0 = (float*)alloc((size_t)N_NODES * 64 * sizeof(float));
  float* H1 = (float*)alloc((size_t)N_NODES * 64 * sizeof(float));

  const int SPMM_GRID = N_NODES / 8;         // 12500 blocks x 4 waves x 2 nodes
  const int GEMM_GRID = (N_NODES + 63) / 64; // 1563 blocks x 4 waves x 16 rows

  // CSR build
  p0_hist_k<<<NBUK, 256, 0, stream>>>(erow, h2d);
  k1_scanb_k<<<NBUK, 256, 0, stream>>>(h2d, btot);
  k2_scanbase_k<<<1, 256, 0, stream>>>(btot, bbase, ep);
  p2_part_k<<<NBUK, 256, 0, stream>>>(erow, ecol, eval, h2d, bbase, pcv, plr);
  p3_fine_k<<<NBUK, 256, 0, stream>>>(pcv, plr, bbase, rp, ep);

  // L1: S = x@W1 ; h1 = relu(A S + b1) -> H0
  gemm_mfma<128, 64><<<GEMM_GRID, 256, 0, stream>>>(x, W1, S);
  spmm16_k<false><<<SPMM_GRID, 256, 0, stream>>>(S, ep, rp, b1, nullptr, H0);

  // L2: S = h1@Wm0 ; h2 = relu(A S + bm0) -> H1
  gemm_mfma<64, 64><<<GEMM_GRID, 256, 0, stream>>>(H0, Wm, S);
  spmm16_k<false><<<SPMM_GRID, 256, 0, stream>>>(S, ep, rp, bm, nullptr, H1);

  // L3..L7 (Wm[1..5]): h = relu(A (prev@Wmk) + bmk) + prev2  (in-place)
  float* prev2 = H0;
  float* prev  = H1;
  for (int k = 1; k < NL; ++k) {
    gemm_mfma<64, 64><<<GEMM_GRID, 256, 0, stream>>>(prev, Wm + (size_t)k * 4096, S);
    spmm16_k<true><<<SPMM_GRID, 256, 0, stream>>>(S, ep, rp, bm + k * 64, prev2, prev2);
    float* t = prev2; prev2 = prev; prev = t;
  }

  // Final: S(64-padded) = h7@W2 ; out = log_softmax(A S + b2)
  gemm_mfma<64, 40><<<GEMM_GRID, 256, 0, stream>>>(prev, W2, S);
  spmm_final_k<<<SPMM_GRID, 256, 0, stream>>>(S, ep, rp, b2, out);
}